// Round 1
// baseline (136.021 us; speedup 1.0000x reference)
//
#include <hip/hip_runtime.h>

// Problem constants (from reference):
//   depth: [B, D, H, W] fp32,  grid: [B, NN*H, W, 2] fp32 in [-1,1]
//   out  : [B, D+NN, H, W] fp32, sorted ascending along channel axis
constexpr int B  = 4;
constexpr int D  = 8;
constexpr int H  = 512;
constexpr int W  = 640;
constexpr int NN = 9;
constexpr int HW = H * W;
constexpr int NC = D + NN;  // 17

__global__ __launch_bounds__(256) void prop_sort_kernel(
    const float* __restrict__ depth,
    const float* __restrict__ grid,
    float* __restrict__ out) {
  int idx = blockIdx.x * blockDim.x + threadIdx.x;
  if (idx >= B * HW) return;

  int b  = idx / HW;
  int hw = idx - b * HW;
  int h  = hw / W;
  int w  = hw - h * W;

  float v[NC];

  // ---- load the 8 depth channels (coalesced plane-strided reads) ----
  const float* dptr = depth + (size_t)b * D * HW + hw;
#pragma unroll
  for (int d = 0; d < D; ++d) {
    v[d] = dptr[(size_t)d * HW];
  }

  // ---- bilinear grid_sample of the center plane, border padding ----
  const float* center = depth + (size_t)b * D * HW + (size_t)(D / 2) * HW;
  // grid viewed as float2 [B, NN*H, W]
  const float2* gp = reinterpret_cast<const float2*>(grid)
                     + ((size_t)b * NN * H + h) * W + w;

#pragma unroll
  for (int n = 0; n < NN; ++n) {
    float2 g = gp[(size_t)n * H * W];
    float gx = g.x, gy = g.y;

    // ix = clip(((gx+1)*W - 1)*0.5, 0, W-1); same for iy with H
    float ix = ((gx + 1.0f) * (float)W - 1.0f) * 0.5f;
    float iy = ((gy + 1.0f) * (float)H - 1.0f) * 0.5f;
    ix = fminf(fmaxf(ix, 0.0f), (float)(W - 1));
    iy = fminf(fmaxf(iy, 0.0f), (float)(H - 1));

    float x0f = floorf(ix);
    float y0f = floorf(iy);
    float wx = ix - x0f;
    float wy = iy - y0f;

    int x0 = (int)x0f;
    int y0 = (int)y0f;
    int x1 = min(x0 + 1, W - 1);
    int y1 = min(y0 + 1, H - 1);

    float v00 = center[y0 * W + x0];
    float v01 = center[y0 * W + x1];
    float v10 = center[y1 * W + x0];
    float v11 = center[y1 * W + x1];

    float vtop = v00 * (1.0f - wx) + v01 * wx;
    float vbot = v10 * (1.0f - wx) + v11 * wx;
    v[D + n] = vtop * (1.0f - wy) + vbot * wy;
  }

  // ---- sort 17 values: branch-free odd-even transposition network ----
  // 17 passes x 8 comparators, fully unrolled, all indices compile-time.
#pragma unroll
  for (int pass = 0; pass < NC; ++pass) {
#pragma unroll
    for (int i = (pass & 1); i + 1 < NC; i += 2) {
      float lo = fminf(v[i], v[i + 1]);
      float hi = fmaxf(v[i], v[i + 1]);
      v[i] = lo;
      v[i + 1] = hi;
    }
  }

  // ---- write 17 output planes (coalesced) ----
  float* optr = out + (size_t)b * NC * HW + hw;
#pragma unroll
  for (int c = 0; c < NC; ++c) {
    optr[(size_t)c * HW] = v[c];
  }
}

extern "C" void kernel_launch(void* const* d_in, const int* in_sizes, int n_in,
                              void* d_out, int out_size, void* d_ws, size_t ws_size,
                              hipStream_t stream) {
  const float* depth = (const float*)d_in[0];
  const float* grid  = (const float*)d_in[1];
  float* out = (float*)d_out;

  int total = B * HW;           // 1,310,720 threads (one per output pixel)
  int block = 256;
  int nblocks = (total + block - 1) / block;  // 5120
  prop_sort_kernel<<<nblocks, block, 0, stream>>>(depth, grid, out);
}